// Round 10
// baseline (2573.936 us; speedup 1.0000x reference)
//
#include <hip/hip_runtime.h>
#include <math.h>

#define DC 256
#define NBINS 1024
#define NQ 8
#define NTOK 32768      // B*T
#define D_IN 512
#define DCH 32
#define TOK 64          // tokens per rvq block -> 512 blocks
#define RVQ_THREADS 256
#define RVQ_BLOCKS (NTOK / TOK)
#define MARGIN 0.02f    // fast(MFMA) top-2 gap below which we re-rank with np bits

typedef __attribute__((ext_vector_type(8))) short short8v;   // 8 bf16 (4 VGPR)
typedef __attribute__((ext_vector_type(4))) float f32x4;

// ---- bf16 helpers (RNE, matches hw cvt) ----
__device__ __forceinline__ unsigned short f2bf(float x) {
  unsigned u = __float_as_uint(x);
  return (unsigned short)((u + 0x7fffu + ((u >> 16) & 1u)) >> 16);
}
__device__ __forceinline__ float bf2f(unsigned short h) {
  return __uint_as_float(((unsigned)h) << 16);
}
__device__ __forceinline__ void store8s(unsigned short* dst, const unsigned short* v) {
  uint4 u;
  u.x = v[0] | ((unsigned)v[1] << 16); u.y = v[2] | ((unsigned)v[3] << 16);
  u.z = v[4] | ((unsigned)v[5] << 16); u.w = v[6] | ((unsigned)v[7] << 16);
  *reinterpret_cast<uint4*>(dst) = u;
}
__device__ __forceinline__ short8v load8s(const unsigned short* p) {
  return __builtin_bit_cast(short8v, *reinterpret_cast<const float4*>(p));
}

// ---- numpy pairwise_sum bit-emulation (8 accumulators, 128-block) ----
__device__ __forceinline__ float np_sumsq128(const float* a) {
#pragma clang fp contract(off)
  float r0 = a[0] * a[0], r1 = a[1] * a[1], r2 = a[2] * a[2], r3 = a[3] * a[3];
  float r4 = a[4] * a[4], r5 = a[5] * a[5], r6 = a[6] * a[6], r7 = a[7] * a[7];
  for (int i = 8; i < 128; i += 8) {
    r0 += a[i + 0] * a[i + 0]; r1 += a[i + 1] * a[i + 1];
    r2 += a[i + 2] * a[i + 2]; r3 += a[i + 3] * a[i + 3];
    r4 += a[i + 4] * a[i + 4]; r5 += a[i + 5] * a[i + 5];
    r6 += a[i + 6] * a[i + 6]; r7 += a[i + 7] * a[i + 7];
  }
  return ((r0 + r1) + (r2 + r3)) + ((r4 + r5) + (r6 + r7));
}
__device__ __forceinline__ float np_sumsq256(const float* a) {
#pragma clang fp contract(off)
  float lo = np_sumsq128(a);
  float hi = np_sumsq128(a + 128);
  return lo + hi;
}

// ---------------- K0: codebook squared norms, np-pairwise bits ----------------
__global__ void e2_np_kernel(const float* __restrict__ cb, float* __restrict__ e2) {
  int b = blockIdx.x * 256 + threadIdx.x;
  e2[b] = np_sumsq256(cb + (size_t)b * DC);
}

// ---------------- K0b: codebook bf16 hi/lo pre-split ----------------
// layout: [s][k8 0..31][bin 0..1023][8] bf16
__global__ void presplit_kernel(const float* __restrict__ cb,
                                unsigned short* __restrict__ cb_h,
                                unsigned short* __restrict__ cb_l) {
  int id = blockIdx.x * 256 + threadIdx.x;   // (s*32+k8)*1024 + bin
  int sk = id >> 10, bin = id & 1023;
  int s = sk >> 5, k8 = sk & 31;
  const float* src = cb + ((size_t)s * NBINS + bin) * DC + k8 * 8;
  unsigned short hh[8], ll[8];
#pragma unroll
  for (int j = 0; j < 8; ++j) {
    float x = src[j];
    unsigned short h = f2bf(x);
    hh[j] = h;
    ll[j] = f2bf(x - bf2f(h));
  }
  store8s(cb_h + (size_t)id * 8, hh);
  store8s(cb_l + (size_t)id * 8, ll);
}

// ---------------- K1: in-projection, OpenBLAS-sgemm bit-emulation ----------------
__global__ __launch_bounds__(256) void in_proj_kernel(
    const float* __restrict__ x, const float* __restrict__ in_w,
    const float* __restrict__ in_b, float* __restrict__ res) {
  __shared__ __align__(16) float aT[DCH][68];
  __shared__ __align__(16) float bT[DCH][68];
  const int thr = threadIdx.x;
  const int tx = thr & 15, ty = thr >> 4;
  const int m0 = blockIdx.x * 64, n0 = blockIdx.y * 64;
  float acc[4][4] = {};
  float s1[4][4] = {};
  for (int kc = 0; kc < D_IN; kc += DCH) {
    if (kc == 384) {
#pragma unroll
      for (int i = 0; i < 4; ++i)
#pragma unroll
        for (int j = 0; j < 4; ++j) { s1[i][j] = acc[i][j]; acc[i][j] = 0.f; }
    }
    __syncthreads();
#pragma unroll
    for (int i = 0; i < 2; ++i) {
      int q = thr + 256 * i;
      int m = q >> 3, kk = (q & 7) << 2;
      float4 v = *reinterpret_cast<const float4*>(x + (size_t)(m0 + m) * D_IN + kc + kk);
      aT[kk + 0][m] = v.x; aT[kk + 1][m] = v.y; aT[kk + 2][m] = v.z; aT[kk + 3][m] = v.w;
      float4 w = *reinterpret_cast<const float4*>(in_w + (size_t)(n0 + m) * D_IN + kc + kk);
      bT[kk + 0][m] = w.x; bT[kk + 1][m] = w.y; bT[kk + 2][m] = w.z; bT[kk + 3][m] = w.w;
    }
    __syncthreads();
#pragma unroll 8
    for (int d = 0; d < DCH; ++d) {
      float4 a = *reinterpret_cast<const float4*>(&aT[d][ty * 4]);
      float4 b = *reinterpret_cast<const float4*>(&bT[d][tx * 4]);
      float av[4] = {a.x, a.y, a.z, a.w};
      float bv[4] = {b.x, b.y, b.z, b.w};
#pragma unroll
      for (int i = 0; i < 4; ++i)
#pragma unroll
        for (int j = 0; j < 4; ++j) acc[i][j] = fmaf(av[i], bv[j], acc[i][j]);
    }
  }
#pragma unroll
  for (int i = 0; i < 4; ++i) {
    int m = m0 + ty * 4 + i, n = n0 + tx * 4;
    float4 hv;
#pragma unroll
    for (int j = 0; j < 4; ++j) {
#pragma clang fp contract(off)
      float c = s1[i][j] + acc[i][j];
      float pre = c + in_b[n + j];
      ((float*)&hv)[j] = tanhf(pre);
    }
    *reinterpret_cast<float4*>(res + (size_t)m * DC + n) = hv;
  }
}

// ---------------- K2: fused 8-stage RVQ — MFMA + LDS dbuf B + np re-rank ----------------
// Waves partition bins; A(-2r hi/lo) in LDS; B staged global->reg->LDS one kstep
// ahead; top-2 merged into per-wave LDS slots (no VGPR spill).
__global__ __launch_bounds__(RVQ_THREADS) void rvq_kernel(
    const float* __restrict__ cb, const float* __restrict__ e2,
    const unsigned short* __restrict__ cb_h, const unsigned short* __restrict__ cb_l,
    float* __restrict__ res, float* __restrict__ idx_f, double* __restrict__ partial) {
  extern __shared__ __align__(16) unsigned char smem[];
  unsigned short* a_hi = (unsigned short*)smem;            // [k8=32][row=64][8] 32KB
  unsigned short* a_lo = (unsigned short*)(smem + 32768);  // 32KB
  unsigned short* bbuf = (unsigned short*)(smem + 65536);  // [2][hi/lo][k8l=4][256][8] 64KB
  float* m1s   = (float*)(smem + 131072);                  // [4][64]
  float* m2s   = (float*)(smem + 132096);
  int*   i1s   = (int*)(smem + 133120);
  int*   win_l = (int*)(smem + 134144);
  int*   flag_l= (int*)(smem + 134400);
  float* rrow_s= (float*)(smem + 134656);                  // 1KB
  float* redf  = (float*)(smem + 135680);
  int*   redi  = (int*)(smem + 135696);
  double* wsum = (double*)(smem + 135712);

  const int thr = threadIdx.x;
  const int lane = thr & 63;
  const int w = thr >> 6;        // wave 0..3 -> bins w*64.. within chunk
  const int lg = lane >> 4;      // k-subgroup (A/B), row-subgroup (C)
  const int lc = lane & 15;      // A row-in-tile / B,C col(bin)-in-tile
  const int m0 = blockIdx.x * TOK;
  double sqacc = 0.0;

  // ---- initial A build: -2*r as bf16 hi/lo into LDS ----
  {
    int row = thr >> 2, d0 = (thr & 3) << 6;
    const float* rrow = res + (size_t)(m0 + row) * DC + d0;
#pragma unroll
    for (int c = 0; c < 8; ++c) {
      float4 r0 = *reinterpret_cast<const float4*>(rrow + c * 8);
      float4 r1 = *reinterpret_cast<const float4*>(rrow + c * 8 + 4);
      float rv[8] = {r0.x, r0.y, r0.z, r0.w, r1.x, r1.y, r1.z, r1.w};
      unsigned short hh[8], ll[8];
#pragma unroll
      for (int j = 0; j < 8; ++j) {
        float xv = -2.0f * rv[j];
        unsigned short h = f2bf(xv);
        hh[j] = h; ll[j] = f2bf(xv - bf2f(h));
      }
      int k8 = (d0 >> 3) + c;
      store8s(a_hi + (k8 * 64 + row) * 8, hh);
      store8s(a_lo + (k8 * 64 + row) * 8, ll);
    }
  }
  // ---- prologue: stage (s=0, unit=0) B tile into buf 0 ----
  {
#pragma unroll
    for (int r = 0; r < 8; ++r) {
      int r4 = r & 3;
      const unsigned short* src = (r < 4 ? cb_h : cb_l) + ((size_t)r4 * 1024 + thr) * 8;
      float4 v = *reinterpret_cast<const float4*>(src);
      *reinterpret_cast<float4*>(bbuf + (r >> 2) * 8192 + r4 * 2048 + thr * 8) = v;
    }
  }
  __syncthreads();

  for (int s = 0; s < NQ; ++s) {
    const float* cbs = cb + (size_t)s * NBINS * DC;
    const float* e2s = e2 + s * NBINS;

    // reset per-wave top-2 slots
    m1s[thr] = 3.4028235e38f; m2s[thr] = 3.4028235e38f; i1s[thr] = 0;
    __syncthreads();

    f32x4 acc[4][4];
    float4 nxt[8];
    for (int u = 0; u < 32; ++u) {
      const int chunk = u >> 3, kstep = u & 7;
      const int bc = chunk * 256;
      const int par = (s * 32 + u) & 1;
      if (kstep == 0) {
#pragma unroll
        for (int nt = 0; nt < 4; ++nt) {
          float ev = e2s[bc + w * 64 + nt * 16 + lc];
          f32x4 iv = {ev, ev, ev, ev};
#pragma unroll
          for (int rt = 0; rt < 4; ++rt) acc[rt][nt] = iv;
        }
      }
      // issue next-unit global loads -> regs (latency hides under MFMA)
      int un = u + 1, sn = s;
      if (un == 32) { un = 0; ++sn; }
      const bool have_next = (sn < NQ);
      if (have_next) {
        int cn = (un >> 3) * 256, kn = un & 7;
        const unsigned short* hp = cb_h + (size_t)sn * (32 * 1024 * 8);
        const unsigned short* lp = cb_l + (size_t)sn * (32 * 1024 * 8);
#pragma unroll
        for (int r = 0; r < 8; ++r) {
          int r4 = r & 3;
          const unsigned short* src =
              (r < 4 ? hp : lp) + ((size_t)(kn * 4 + r4) * 1024 + cn + thr) * 8;
          nxt[r] = *reinterpret_cast<const float4*>(src);
        }
      }
      // fragment reads + MFMA (3-pass hi/lo)
      {
        short8v ah[4], al[4];
#pragma unroll
        for (int rt = 0; rt < 4; ++rt) {
          int off = ((kstep * 4 + lg) * 64 + rt * 16 + lc) * 8;
          ah[rt] = load8s(a_hi + off);
          al[rt] = load8s(a_lo + off);
        }
#pragma unroll
        for (int nt = 0; nt < 4; ++nt) {
          int boff = par * 16384 + lg * 2048 + (w * 64 + nt * 16 + lc) * 8;
          short8v bh = load8s(bbuf + boff);
          short8v bl = load8s(bbuf + boff + 8192);
#pragma unroll
          for (int rt = 0; rt < 4; ++rt) {
            acc[rt][nt] = __builtin_amdgcn_mfma_f32_16x16x32_bf16(ah[rt], bh, acc[rt][nt], 0, 0, 0);
            acc[rt][nt] = __builtin_amdgcn_mfma_f32_16x16x32_bf16(ah[rt], bl, acc[rt][nt], 0, 0, 0);
            acc[rt][nt] = __builtin_amdgcn_mfma_f32_16x16x32_bf16(al[rt], bh, acc[rt][nt], 0, 0, 0);
          }
        }
      }
      // fold chunk's dists into per-wave LDS top-2 (bins ascending)
      if (kstep == 7) {
#pragma unroll
        for (int rt = 0; rt < 4; ++rt)
#pragma unroll
          for (int reg = 0; reg < 4; ++reg) {
            float m1 = 3.4028235e38f, m2 = 3.4028235e38f; int i1 = 0;
#pragma unroll
            for (int nt = 0; nt < 4; ++nt) {
              float v = acc[rt][nt][reg];
              int b = bc + w * 64 + nt * 16 + lc;
              if (v < m1) { m2 = m1; m1 = v; i1 = b; }
              else m2 = fminf(m2, v);
            }
#pragma unroll
            for (int msk = 1; msk < 16; msk <<= 1) {
              float om1 = __shfl_xor(m1, msk, 64);
              float om2 = __shfl_xor(m2, msk, 64);
              int   oi1 = __shfl_xor(i1, msk, 64);
              if (om1 < m1 || (om1 == m1 && oi1 < i1)) { m2 = fminf(m1, om2); m1 = om1; i1 = oi1; }
              else m2 = fminf(m2, om1);
            }
            if (lc == 0) {
              int sidx = w * 64 + rt * 16 + lg * 4 + reg;
              float pm1 = m1s[sidx], pm2 = m2s[sidx]; int pi1 = i1s[sidx];
              if (m1 < pm1 || (m1 == pm1 && i1 < pi1)) {
                m1s[sidx] = m1; m2s[sidx] = fminf(pm1, m2); i1s[sidx] = i1;
              } else {
                m2s[sidx] = fminf(pm2, m1);
              }
            }
          }
      }
      // write staged regs -> other buffer (prev readers of it finished last barrier)
      if (have_next) {
        int pn = par ^ 1;
#pragma unroll
        for (int r = 0; r < 8; ++r)
          *reinterpret_cast<float4*>(bbuf + pn * 16384 + (r >> 2) * 8192 + (r & 3) * 2048 + thr * 8) = nxt[r];
      }
      __syncthreads();
    }
    // final per-row merge across waves -> winner + margin flag
    if (thr < TOK) {
      float m1 = m1s[thr], m2 = m2s[thr]; int i1 = i1s[thr];
#pragma unroll
      for (int ww = 1; ww < 4; ++ww) {
        float om1 = m1s[ww * 64 + thr], om2 = m2s[ww * 64 + thr];
        int oi1 = i1s[ww * 64 + thr];
        if (om1 < m1 || (om1 == m1 && oi1 < i1)) { m2 = fminf(m1, om2); m1 = om1; i1 = oi1; }
        else m2 = fminf(m2, om1);
      }
      win_l[thr] = i1;
      flag_l[thr] = (m2 - m1 < MARGIN) ? 1 : 0;
    }
    __syncthreads();
    // ---- np-bit re-rank for flagged rows (rare; uniform branch) ----
    for (int row = 0; row < TOK; ++row) {
      if (!flag_l[row]) continue;
      if (thr < 64)
        reinterpret_cast<float4*>(rrow_s)[thr] =
            reinterpret_cast<const float4*>(res + (size_t)(m0 + row) * DC)[thr];
      __syncthreads();
      float r2 = np_sumsq256(rrow_s);
      float best = 3.4028235e38f; int bb = 0;
#pragma unroll
      for (int jj = 0; jj < 4; ++jj) {
        int b = thr * 4 + jj;
        const float4* e4 = reinterpret_cast<const float4*>(cbs + (size_t)b * DC);
        const float4* r4 = reinterpret_cast<const float4*>(rrow_s);
        float accv = 0.f;
        for (int q = 0; q < 64; ++q) {   // d ascending: sgemm-chain bits
          float4 ev = e4[q], rv = r4[q];
          accv = fmaf(rv.x, ev.x, accv);
          accv = fmaf(rv.y, ev.y, accv);
          accv = fmaf(rv.z, ev.z, accv);
          accv = fmaf(rv.w, ev.w, accv);
        }
        {
#pragma clang fp contract(off)
          float t = r2 - 2.0f * accv;
          float dist = t + e2s[b];
          if (dist < best) { best = dist; bb = b; }
        }
      }
#pragma unroll
      for (int msk = 1; msk < 64; msk <<= 1) {
        float ov = __shfl_xor(best, msk, 64);
        int   ob = __shfl_xor(bb, msk, 64);
        if (ov < best || (ov == best && ob < bb)) { best = ov; bb = ob; }
      }
      if (lane == 0) { redf[w] = best; redi[w] = bb; }
      __syncthreads();
      if (thr == 0) {
        float bs = redf[0]; int bfin = redi[0];
#pragma unroll
        for (int ww = 1; ww < 4; ++ww)
          if (redf[ww] < bs || (redf[ww] == bs && redi[ww] < bfin)) { bs = redf[ww]; bfin = redi[ww]; }
        win_l[row] = bfin;
      }
      __syncthreads();
    }
    // ---- residual update (np state bits) + commit acc + A rebuild ----
    {
      int row = thr >> 2, d0 = (thr & 3) << 6;
      int wbin = win_l[row];
      const float* erow = cbs + (size_t)wbin * DC + d0;
      float* rrow = res + (size_t)(m0 + row) * DC + d0;
#pragma unroll
      for (int c = 0; c < 8; ++c) {
        float4 r0 = *reinterpret_cast<const float4*>(rrow + c * 8);
        float4 r1 = *reinterpret_cast<const float4*>(rrow + c * 8 + 4);
        float4 e0 = *reinterpret_cast<const float4*>(erow + c * 8);
        float4 e1 = *reinterpret_cast<const float4*>(erow + c * 8 + 4);
        float nv[8] = {r0.x - e0.x, r0.y - e0.y, r0.z - e0.z, r0.w - e0.w,
                       r1.x - e1.x, r1.y - e1.y, r1.z - e1.z, r1.w - e1.w};
        unsigned short hh[8], ll[8];
#pragma unroll
        for (int j = 0; j < 8; ++j) {
          sqacc += (double)nv[j] * nv[j];
          float xv = -2.0f * nv[j];
          unsigned short h = f2bf(xv);
          hh[j] = h; ll[j] = f2bf(xv - bf2f(h));
        }
        *reinterpret_cast<float4*>(rrow + c * 8) = (float4){nv[0], nv[1], nv[2], nv[3]};
        *reinterpret_cast<float4*>(rrow + c * 8 + 4) = (float4){nv[4], nv[5], nv[6], nv[7]};
        int k8 = (d0 >> 3) + c;
        store8s(a_hi + (k8 * 64 + row) * 8, hh);
        store8s(a_lo + (k8 * 64 + row) * 8, ll);
      }
      if (thr < TOK) idx_f[(size_t)s * NTOK + m0 + thr] = (float)win_l[thr];
    }
    __syncthreads();
  }
  // deterministic per-block commit partial (fp64)
#pragma unroll
  for (int msk = 1; msk < 64; msk <<= 1) sqacc += __shfl_xor(sqacc, msk, 64);
  if (lane == 0) wsum[w] = sqacc;
  __syncthreads();
  if (thr == 0) {
    double t = 0.0;
#pragma unroll
    for (int ww = 0; ww < 4; ++ww) t += wsum[ww];
    partial[blockIdx.x] = t;
  }
}

// ---------------- K4: finalize commit loss ----------------
__global__ void finalize_kernel(const double* __restrict__ partial, float* __restrict__ out_last) {
  if (threadIdx.x == 0 && blockIdx.x == 0) {
    double t = 0.0;
    for (int i = 0; i < RVQ_BLOCKS; ++i) t += partial[i];
    out_last[0] = (float)(0.1 * t / 8388608.0);
  }
}

// ---------------- K3: out-projection GEMM from gathered quantized ----------------
__global__ __launch_bounds__(256) void out_proj_kernel(
    const float* __restrict__ cb, const float* __restrict__ idx_f,
    const float* __restrict__ out_w, const float* __restrict__ out_b,
    float* __restrict__ out) {
  __shared__ __align__(16) float aT[DCH][68];
  __shared__ __align__(16) float bT[DCH][68];
  __shared__ int idx_l[NQ][64];
  const int thr = threadIdx.x;
  const int tx = thr & 15, ty = thr >> 4;
  const int m0 = blockIdx.x * 64, n0 = blockIdx.y * 64;
#pragma unroll
  for (int i = 0; i < 2; ++i) {
    int q = thr + 256 * i;
    int s = q >> 6, m = q & 63;
    idx_l[s][m] = (int)idx_f[(size_t)s * NTOK + m0 + m];
  }
  float acc[4][4] = {};
  for (int kc = 0; kc < DC; kc += DCH) {
    __syncthreads();
#pragma unroll
    for (int i = 0; i < 2; ++i) {
      int q = thr + 256 * i;
      int m = q >> 3, kk = (q & 7) << 2;
      float4 v = {0.f, 0.f, 0.f, 0.f};
#pragma unroll
      for (int s = 0; s < NQ; ++s) {
        const float4 e = *reinterpret_cast<const float4*>(
            cb + ((size_t)s * NBINS + idx_l[s][m]) * DC + kc + kk);
        v.x += e.x; v.y += e.y; v.z += e.z; v.w += e.w;
      }
      aT[kk + 0][m] = v.x; aT[kk + 1][m] = v.y; aT[kk + 2][m] = v.z; aT[kk + 3][m] = v.w;
      float4 wv = *reinterpret_cast<const float4*>(out_w + (size_t)(n0 + m) * DC + kc + kk);
      bT[kk + 0][m] = wv.x; bT[kk + 1][m] = wv.y; bT[kk + 2][m] = wv.z; bT[kk + 3][m] = wv.w;
    }
    __syncthreads();
#pragma unroll 8
    for (int d = 0; d < DCH; ++d) {
      float4 a = *reinterpret_cast<const float4*>(&aT[d][ty * 4]);
      float4 b = *reinterpret_cast<const float4*>(&bT[d][tx * 4]);
      float av[4] = {a.x, a.y, a.z, a.w};
      float bv[4] = {b.x, b.y, b.z, b.w};
#pragma unroll
      for (int i = 0; i < 4; ++i)
#pragma unroll
        for (int j = 0; j < 4; ++j) acc[i][j] = fmaf(av[i], bv[j], acc[i][j]);
    }
  }
#pragma unroll
  for (int i = 0; i < 4; ++i) {
    int m = m0 + ty * 4 + i, n = n0 + tx * 4;
    float4 o;
    o.x = acc[i][0] + out_b[n + 0];
    o.y = acc[i][1] + out_b[n + 1];
    o.z = acc[i][2] + out_b[n + 2];
    o.w = acc[i][3] + out_b[n + 3];
    *reinterpret_cast<float4*>(out + (size_t)m * D_IN + n) = o;
  }
}

extern "C" void kernel_launch(void* const* d_in, const int* in_sizes, int n_in,
                              void* d_out, int out_size, void* d_ws, size_t ws_size,
                              hipStream_t stream) {
  (void)in_sizes; (void)n_in; (void)out_size; (void)d_ws; (void)ws_size;
  const float* x     = (const float*)d_in[0];
  const float* in_w  = (const float*)d_in[1];
  const float* in_b  = (const float*)d_in[2];
  const float* out_w = (const float*)d_in[3];
  const float* out_b = (const float*)d_in[4];
  const float* cb    = (const float*)d_in[5];
  float* out = (float*)d_out;
  // d_out scratch layout (consumed before out_proj overwrites [0,16.7M)):
  float* res    = out;                                  // 8,388,608 f32 residual
  float* e2     = out + 8388608;                        // 8192 f32 (np bits)
  double* part  = (double*)(out + 8404992);             // 512 f64
  unsigned short* cb_h = (unsigned short*)(out + 9000000);   // 2,097,152 bf16 (4MB)
  unsigned short* cb_l = (unsigned short*)(out + 10500000);  // 4MB
  float* idx_f  = out + 16777216;                       // 262,144 f32
  float* c_out  = out + 17039360;                       // 1 f32

  hipLaunchKernelGGL(e2_np_kernel, dim3(32), dim3(256), 0, stream, cb, e2);
  hipLaunchKernelGGL(presplit_kernel, dim3(1024), dim3(256), 0, stream, cb, cb_h, cb_l);
  hipLaunchKernelGGL(in_proj_kernel, dim3(512, 4), dim3(256), 0, stream, x, in_w, in_b, res);
  hipLaunchKernelGGL(rvq_kernel, dim3(RVQ_BLOCKS), dim3(RVQ_THREADS), 135744, stream,
                     cb, e2, cb_h, cb_l, res, idx_f, part);
  hipLaunchKernelGGL(finalize_kernel, dim3(1), dim3(64), 0, stream, part, c_out);
  hipLaunchKernelGGL(out_proj_kernel, dim3(512, 8), dim3(256), 0, stream, cb, idx_f, out_w, out_b, out);
}

// Round 11
// 2478.917 us; speedup vs baseline: 1.0383x; 1.0383x over previous
//
#include <hip/hip_runtime.h>
#include <math.h>

#define DC 256
#define NBINS 1024
#define NQ 8
#define NTOK 32768      // B*T
#define D_IN 512
#define DCH 32
#define TOK 64          // tokens per stage-block -> 512 blocks/stage
#define STG_BLOCKS (NTOK / TOK)
#define MARGIN 0.02f    // fast(MFMA) top-2 gap below which we re-rank with np bits

typedef __attribute__((ext_vector_type(8))) short short8v;   // 8 bf16 (4 VGPR)
typedef __attribute__((ext_vector_type(4))) float f32x4;

// ---- bf16 helpers (RNE, matches hw cvt) ----
__device__ __forceinline__ unsigned short f2bf(float x) {
  unsigned u = __float_as_uint(x);
  return (unsigned short)((u + 0x7fffu + ((u >> 16) & 1u)) >> 16);
}
__device__ __forceinline__ float bf2f(unsigned short h) {
  return __uint_as_float(((unsigned)h) << 16);
}
__device__ __forceinline__ void store8s(unsigned short* dst, const unsigned short* v) {
  uint4 u;
  u.x = v[0] | ((unsigned)v[1] << 16); u.y = v[2] | ((unsigned)v[3] << 16);
  u.z = v[4] | ((unsigned)v[5] << 16); u.w = v[6] | ((unsigned)v[7] << 16);
  *reinterpret_cast<uint4*>(dst) = u;
}
__device__ __forceinline__ short8v load8s(const unsigned short* p) {
  return __builtin_bit_cast(short8v, *reinterpret_cast<const float4*>(p));
}

// ---- numpy pairwise_sum bit-emulation (8 accumulators, 128-block) ----
__device__ __forceinline__ float np_sumsq128(const float* a) {
#pragma clang fp contract(off)
  float r0 = a[0] * a[0], r1 = a[1] * a[1], r2 = a[2] * a[2], r3 = a[3] * a[3];
  float r4 = a[4] * a[4], r5 = a[5] * a[5], r6 = a[6] * a[6], r7 = a[7] * a[7];
  for (int i = 8; i < 128; i += 8) {
    r0 += a[i + 0] * a[i + 0]; r1 += a[i + 1] * a[i + 1];
    r2 += a[i + 2] * a[i + 2]; r3 += a[i + 3] * a[i + 3];
    r4 += a[i + 4] * a[i + 4]; r5 += a[i + 5] * a[i + 5];
    r6 += a[i + 6] * a[i + 6]; r7 += a[i + 7] * a[i + 7];
  }
  return ((r0 + r1) + (r2 + r3)) + ((r4 + r5) + (r6 + r7));
}
__device__ __forceinline__ float np_sumsq256(const float* a) {
#pragma clang fp contract(off)
  float lo = np_sumsq128(a);
  float hi = np_sumsq128(a + 128);
  return lo + hi;
}

// ---------------- K0: codebook squared norms, np-pairwise bits ----------------
__global__ void e2_np_kernel(const float* __restrict__ cb, float* __restrict__ e2) {
  int b = blockIdx.x * 256 + threadIdx.x;
  e2[b] = np_sumsq256(cb + (size_t)b * DC);
}

// ---------------- K0b: codebook bf16 hi/lo pre-split ----------------
// layout: [s][k8 0..31][bin 0..1023][8] bf16
__global__ void presplit_kernel(const float* __restrict__ cb,
                                unsigned short* __restrict__ cb_h,
                                unsigned short* __restrict__ cb_l) {
  int id = blockIdx.x * 256 + threadIdx.x;   // (s*32+k8)*1024 + bin
  int sk = id >> 10, bin = id & 1023;
  int s = sk >> 5, k8 = sk & 31;
  const float* src = cb + ((size_t)s * NBINS + bin) * DC + k8 * 8;
  unsigned short hh[8], ll[8];
#pragma unroll
  for (int j = 0; j < 8; ++j) {
    float x = src[j];
    unsigned short h = f2bf(x);
    hh[j] = h;
    ll[j] = f2bf(x - bf2f(h));
  }
  store8s(cb_h + (size_t)id * 8, hh);
  store8s(cb_l + (size_t)id * 8, ll);
}

// ---------------- K1: in-projection, OpenBLAS-sgemm bit-emulation ----------------
__global__ __launch_bounds__(256) void in_proj_kernel(
    const float* __restrict__ x, const float* __restrict__ in_w,
    const float* __restrict__ in_b, float* __restrict__ res) {
  __shared__ __align__(16) float aT[DCH][68];
  __shared__ __align__(16) float bT[DCH][68];
  const int thr = threadIdx.x;
  const int tx = thr & 15, ty = thr >> 4;
  const int m0 = blockIdx.x * 64, n0 = blockIdx.y * 64;
  float acc[4][4] = {};
  float s1[4][4] = {};
  for (int kc = 0; kc < D_IN; kc += DCH) {
    if (kc == 384) {
#pragma unroll
      for (int i = 0; i < 4; ++i)
#pragma unroll
        for (int j = 0; j < 4; ++j) { s1[i][j] = acc[i][j]; acc[i][j] = 0.f; }
    }
    __syncthreads();
#pragma unroll
    for (int i = 0; i < 2; ++i) {
      int q = thr + 256 * i;
      int m = q >> 3, kk = (q & 7) << 2;
      float4 v = *reinterpret_cast<const float4*>(x + (size_t)(m0 + m) * D_IN + kc + kk);
      aT[kk + 0][m] = v.x; aT[kk + 1][m] = v.y; aT[kk + 2][m] = v.z; aT[kk + 3][m] = v.w;
      float4 w = *reinterpret_cast<const float4*>(in_w + (size_t)(n0 + m) * D_IN + kc + kk);
      bT[kk + 0][m] = w.x; bT[kk + 1][m] = w.y; bT[kk + 2][m] = w.z; bT[kk + 3][m] = w.w;
    }
    __syncthreads();
#pragma unroll 8
    for (int d = 0; d < DCH; ++d) {
      float4 a = *reinterpret_cast<const float4*>(&aT[d][ty * 4]);
      float4 b = *reinterpret_cast<const float4*>(&bT[d][tx * 4]);
      float av[4] = {a.x, a.y, a.z, a.w};
      float bv[4] = {b.x, b.y, b.z, b.w};
#pragma unroll
      for (int i = 0; i < 4; ++i)
#pragma unroll
        for (int j = 0; j < 4; ++j) acc[i][j] = fmaf(av[i], bv[j], acc[i][j]);
    }
  }
#pragma unroll
  for (int i = 0; i < 4; ++i) {
    int m = m0 + ty * 4 + i, n = n0 + tx * 4;
    float4 hv;
#pragma unroll
    for (int j = 0; j < 4; ++j) {
#pragma clang fp contract(off)
      float c = s1[i][j] + acc[i][j];
      float pre = c + in_b[n + j];
      ((float*)&hv)[j] = tanhf(pre);
    }
    *reinterpret_cast<float4*>(res + (size_t)m * DC + n) = hv;
  }
}

// ---------------- K2: per-stage RVQ — MFMA score + np re-rank + update ----------------
// One launch per stage: all blocks on the same codebook (L2-resident);
// A(-2r hi/lo) in LDS (~70KB -> 2 blocks/CU); B streamed from L2;
// top-2 folded per chunk into per-wave LDS slots (no spill).
__global__ __launch_bounds__(256) void stage_kernel(
    const float* __restrict__ cb, const float* __restrict__ e2,
    const unsigned short* __restrict__ cb_h, const unsigned short* __restrict__ cb_l,
    float* __restrict__ res, float* __restrict__ idx_f, double* __restrict__ partial,
    int s) {
  __shared__ __align__(16) unsigned short a_hi[32 * 64 * 8];  // 32KB
  __shared__ __align__(16) unsigned short a_lo[32 * 64 * 8];  // 32KB
  __shared__ float m1s[4 * 64], m2s[4 * 64];
  __shared__ int   i1s[4 * 64];
  __shared__ int   win_l[64], flag_l[64];
  __shared__ __align__(16) float rrow_s[256];
  __shared__ float redf[4];
  __shared__ int   redi[4];
  __shared__ double wsum[4];

  const int thr = threadIdx.x;
  const int lane = thr & 63;
  const int w = thr >> 6;        // wave 0..3 -> bins [w*256, w*256+256)
  const int lg = lane >> 4;      // k-subgroup (A/B), row-subgroup (C)
  const int lc = lane & 15;      // A row-in-tile / B,C col(bin)-in-tile
  const int m0 = blockIdx.x * TOK;
  const float* cbs = cb + (size_t)s * NBINS * DC;
  const float* e2s = e2 + (size_t)s * NBINS;
  const unsigned short* bhp = cb_h + (size_t)s * (32 * 1024 * 8);
  const unsigned short* blp = cb_l + (size_t)s * (32 * 1024 * 8);
  double sqacc = 0.0;

  // ---- A build: -2*r as bf16 hi/lo into LDS ----
  {
    int row = thr >> 2, d0 = (thr & 3) << 6;
    const float* rrow = res + (size_t)(m0 + row) * DC + d0;
#pragma unroll
    for (int c = 0; c < 8; ++c) {
      float4 r0 = *reinterpret_cast<const float4*>(rrow + c * 8);
      float4 r1 = *reinterpret_cast<const float4*>(rrow + c * 8 + 4);
      float rv[8] = {r0.x, r0.y, r0.z, r0.w, r1.x, r1.y, r1.z, r1.w};
      unsigned short hh[8], ll[8];
#pragma unroll
      for (int j = 0; j < 8; ++j) {
        float xv = -2.0f * rv[j];
        unsigned short h = f2bf(xv);
        hh[j] = h; ll[j] = f2bf(xv - bf2f(h));
      }
      int k8 = (d0 >> 3) + c;
      store8s(a_hi + ((size_t)k8 * 64 + row) * 8, hh);
      store8s(a_lo + ((size_t)k8 * 64 + row) * 8, ll);
    }
  }
  m1s[thr] = 3.4028235e38f; m2s[thr] = 3.4028235e38f; i1s[thr] = 0;
  __syncthreads();

  // ---- MFMA scoring: dist = e2 - 2*r.e, 3-pass bf16 hi/lo ----
  for (int c = 0; c < 4; ++c) {
    const int bbase = w * 256 + c * 64;
    f32x4 acc[4][4];
#pragma unroll
    for (int nt = 0; nt < 4; ++nt) {
      float ev = e2s[bbase + nt * 16 + lc];
      f32x4 iv = {ev, ev, ev, ev};
#pragma unroll
      for (int rt = 0; rt < 4; ++rt) acc[rt][nt] = iv;
    }
#pragma unroll 2
    for (int kstep = 0; kstep < 8; ++kstep) {
      short8v ah[4], al[4];
#pragma unroll
      for (int rt = 0; rt < 4; ++rt) {
        int off = ((kstep * 4 + lg) * 64 + rt * 16 + lc) * 8;
        ah[rt] = load8s(a_hi + off);
        al[rt] = load8s(a_lo + off);
      }
      short8v bh[4], bl[4];
#pragma unroll
      for (int nt = 0; nt < 4; ++nt) {
        size_t boff = ((size_t)(kstep * 4 + lg) * 1024 + bbase + nt * 16 + lc) * 8;
        bh[nt] = load8s(bhp + boff);
        bl[nt] = load8s(blp + boff);
      }
#pragma unroll
      for (int nt = 0; nt < 4; ++nt)
#pragma unroll
        for (int rt = 0; rt < 4; ++rt) {
          acc[rt][nt] = __builtin_amdgcn_mfma_f32_16x16x32_bf16(ah[rt], bh[nt], acc[rt][nt], 0, 0, 0);
          acc[rt][nt] = __builtin_amdgcn_mfma_f32_16x16x32_bf16(ah[rt], bl[nt], acc[rt][nt], 0, 0, 0);
          acc[rt][nt] = __builtin_amdgcn_mfma_f32_16x16x32_bf16(al[rt], bh[nt], acc[rt][nt], 0, 0, 0);
        }
    }
    // fold this chunk into per-wave LDS top-2 (bins ascending)
#pragma unroll
    for (int rt = 0; rt < 4; ++rt)
#pragma unroll
      for (int reg = 0; reg < 4; ++reg) {
        float m1 = 3.4028235e38f, m2 = 3.4028235e38f; int i1 = 0;
#pragma unroll
        for (int nt = 0; nt < 4; ++nt) {
          float v = acc[rt][nt][reg];
          int b = bbase + nt * 16 + lc;
          if (v < m1) { m2 = m1; m1 = v; i1 = b; }
          else m2 = fminf(m2, v);
        }
#pragma unroll
        for (int msk = 1; msk < 16; msk <<= 1) {
          float om1 = __shfl_xor(m1, msk, 64);
          float om2 = __shfl_xor(m2, msk, 64);
          int   oi1 = __shfl_xor(i1, msk, 64);
          if (om1 < m1 || (om1 == m1 && oi1 < i1)) { m2 = fminf(m1, om2); m1 = om1; i1 = oi1; }
          else m2 = fminf(m2, om1);
        }
        if (lc == 0) {
          int sidx = w * 64 + rt * 16 + lg * 4 + reg;
          float pm1 = m1s[sidx], pm2 = m2s[sidx]; int pi1 = i1s[sidx];
          if (m1 < pm1 || (m1 == pm1 && i1 < pi1)) {
            m1s[sidx] = m1; m2s[sidx] = fminf(pm1, m2); i1s[sidx] = i1;
          } else {
            m2s[sidx] = fminf(pm2, m1);
          }
        }
      }
  }
  __syncthreads();
  // final per-row merge across waves -> winner + margin flag
  if (thr < TOK) {
    float m1 = m1s[thr], m2 = m2s[thr]; int i1 = i1s[thr];
#pragma unroll
    for (int ww = 1; ww < 4; ++ww) {
      float om1 = m1s[ww * 64 + thr], om2 = m2s[ww * 64 + thr];
      int oi1 = i1s[ww * 64 + thr];
      if (om1 < m1 || (om1 == m1 && oi1 < i1)) { m2 = fminf(m1, om2); m1 = om1; i1 = oi1; }
      else m2 = fminf(m2, om1);
    }
    win_l[thr] = i1;
    flag_l[thr] = (m2 - m1 < MARGIN) ? 1 : 0;
  }
  __syncthreads();
  // ---- np-bit re-rank for flagged rows (rare; uniform branch) ----
  for (int row = 0; row < TOK; ++row) {
    if (!flag_l[row]) continue;
    if (thr < 64)
      reinterpret_cast<float4*>(rrow_s)[thr] =
          reinterpret_cast<const float4*>(res + (size_t)(m0 + row) * DC)[thr];
    __syncthreads();
    float r2 = np_sumsq256(rrow_s);
    float best = 3.4028235e38f; int bb = 0;
#pragma unroll
    for (int jj = 0; jj < 4; ++jj) {
      int b = thr * 4 + jj;
      const float4* e4 = reinterpret_cast<const float4*>(cbs + (size_t)b * DC);
      const float4* r4 = reinterpret_cast<const float4*>(rrow_s);
      float accv = 0.f;
      for (int q = 0; q < 64; ++q) {   // d ascending: sgemm-chain bits
        float4 ev = e4[q], rv = r4[q];
        accv = fmaf(rv.x, ev.x, accv);
        accv = fmaf(rv.y, ev.y, accv);
        accv = fmaf(rv.z, ev.z, accv);
        accv = fmaf(rv.w, ev.w, accv);
      }
      {
#pragma clang fp contract(off)
        float t = r2 - 2.0f * accv;
        float dist = t + e2s[b];
        if (dist < best) { best = dist; bb = b; }
      }
    }
#pragma unroll
    for (int msk = 1; msk < 64; msk <<= 1) {
      float ov = __shfl_xor(best, msk, 64);
      int   ob = __shfl_xor(bb, msk, 64);
      if (ov < best || (ov == best && ob < bb)) { best = ov; bb = ob; }
    }
    if (lane == 0) { redf[w] = best; redi[w] = bb; }
    __syncthreads();
    if (thr == 0) {
      float bs = redf[0]; int bfin = redi[0];
#pragma unroll
      for (int ww = 1; ww < 4; ++ww)
        if (redf[ww] < bs || (redf[ww] == bs && redi[ww] < bfin)) { bs = redf[ww]; bfin = redi[ww]; }
      win_l[row] = bfin;
    }
    __syncthreads();
  }
  // ---- residual update (np state bits) + commit acc ----
  {
    int row = thr >> 2, d0 = (thr & 3) << 6;
    int wbin = win_l[row];
    const float* erow = cbs + (size_t)wbin * DC + d0;
    float* rrow = res + (size_t)(m0 + row) * DC + d0;
#pragma unroll
    for (int c = 0; c < 8; ++c) {
      float4 r0 = *reinterpret_cast<const float4*>(rrow + c * 8);
      float4 r1 = *reinterpret_cast<const float4*>(rrow + c * 8 + 4);
      float4 e0 = *reinterpret_cast<const float4*>(erow + c * 8);
      float4 e1 = *reinterpret_cast<const float4*>(erow + c * 8 + 4);
      float nv[8] = {r0.x - e0.x, r0.y - e0.y, r0.z - e0.z, r0.w - e0.w,
                     r1.x - e1.x, r1.y - e1.y, r1.z - e1.z, r1.w - e1.w};
#pragma unroll
      for (int j = 0; j < 8; ++j) sqacc += (double)nv[j] * nv[j];
      *reinterpret_cast<float4*>(rrow + c * 8) = (float4){nv[0], nv[1], nv[2], nv[3]};
      *reinterpret_cast<float4*>(rrow + c * 8 + 4) = (float4){nv[4], nv[5], nv[6], nv[7]};
    }
    if (thr < TOK) idx_f[(size_t)s * NTOK + m0 + thr] = (float)win_l[thr];
  }
  // deterministic per-block commit partial (fp64)
#pragma unroll
  for (int msk = 1; msk < 64; msk <<= 1) sqacc += __shfl_xor(sqacc, msk, 64);
  if (lane == 0) wsum[w] = sqacc;
  __syncthreads();
  if (thr == 0) {
    double t = 0.0;
#pragma unroll
    for (int ww = 0; ww < 4; ++ww) t += wsum[ww];
    partial[(size_t)s * STG_BLOCKS + blockIdx.x] = t;
  }
}

// ---------------- K4: finalize commit loss (fixed order, 8*512 partials) ----------------
__global__ void finalize_kernel(const double* __restrict__ partial, float* __restrict__ out_last) {
  __shared__ double acc_s[64];
  int t = threadIdx.x;
  double a = 0.0;
  for (int i = 0; i < 64; ++i) a += partial[(size_t)t * 64 + i];
  acc_s[t] = a;
  __syncthreads();
  if (t == 0) {
    double tot = 0.0;
    for (int i = 0; i < 64; ++i) tot += acc_s[i];
    out_last[0] = (float)(0.1 * tot / 8388608.0);
  }
}

// ---------------- K3: out-projection GEMM from gathered quantized ----------------
__global__ __launch_bounds__(256) void out_proj_kernel(
    const float* __restrict__ cb, const float* __restrict__ idx_f,
    const float* __restrict__ out_w, const float* __restrict__ out_b,
    float* __restrict__ out) {
  __shared__ __align__(16) float aT[DCH][68];
  __shared__ __align__(16) float bT[DCH][68];
  __shared__ int idx_l[NQ][64];
  const int thr = threadIdx.x;
  const int tx = thr & 15, ty = thr >> 4;
  const int m0 = blockIdx.x * 64, n0 = blockIdx.y * 64;
#pragma unroll
  for (int i = 0; i < 2; ++i) {
    int q = thr + 256 * i;
    int s = q >> 6, m = q & 63;
    idx_l[s][m] = (int)idx_f[(size_t)s * NTOK + m0 + m];
  }
  float acc[4][4] = {};
  for (int kc = 0; kc < DC; kc += DCH) {
    __syncthreads();
#pragma unroll
    for (int i = 0; i < 2; ++i) {
      int q = thr + 256 * i;
      int m = q >> 3, kk = (q & 7) << 2;
      float4 v = {0.f, 0.f, 0.f, 0.f};
#pragma unroll
      for (int s = 0; s < NQ; ++s) {
        const float4 e = *reinterpret_cast<const float4*>(
            cb + ((size_t)s * NBINS + idx_l[s][m]) * DC + kc + kk);
        v.x += e.x; v.y += e.y; v.z += e.z; v.w += e.w;
      }
      aT[kk + 0][m] = v.x; aT[kk + 1][m] = v.y; aT[kk + 2][m] = v.z; aT[kk + 3][m] = v.w;
      float4 wv = *reinterpret_cast<const float4*>(out_w + (size_t)(n0 + m) * DC + kc + kk);
      bT[kk + 0][m] = wv.x; bT[kk + 1][m] = wv.y; bT[kk + 2][m] = wv.z; bT[kk + 3][m] = wv.w;
    }
    __syncthreads();
#pragma unroll 8
    for (int d = 0; d < DCH; ++d) {
      float4 a = *reinterpret_cast<const float4*>(&aT[d][ty * 4]);
      float4 b = *reinterpret_cast<const float4*>(&bT[d][tx * 4]);
      float av[4] = {a.x, a.y, a.z, a.w};
      float bv[4] = {b.x, b.y, b.z, b.w};
#pragma unroll
      for (int i = 0; i < 4; ++i)
#pragma unroll
        for (int j = 0; j < 4; ++j) acc[i][j] = fmaf(av[i], bv[j], acc[i][j]);
    }
  }
#pragma unroll
  for (int i = 0; i < 4; ++i) {
    int m = m0 + ty * 4 + i, n = n0 + tx * 4;
    float4 o;
    o.x = acc[i][0] + out_b[n + 0];
    o.y = acc[i][1] + out_b[n + 1];
    o.z = acc[i][2] + out_b[n + 2];
    o.w = acc[i][3] + out_b[n + 3];
    *reinterpret_cast<float4*>(out + (size_t)m * D_IN + n) = o;
  }
}

extern "C" void kernel_launch(void* const* d_in, const int* in_sizes, int n_in,
                              void* d_out, int out_size, void* d_ws, size_t ws_size,
                              hipStream_t stream) {
  (void)in_sizes; (void)n_in; (void)out_size; (void)d_ws; (void)ws_size;
  const float* x     = (const float*)d_in[0];
  const float* in_w  = (const float*)d_in[1];
  const float* in_b  = (const float*)d_in[2];
  const float* out_w = (const float*)d_in[3];
  const float* out_b = (const float*)d_in[4];
  const float* cb    = (const float*)d_in[5];
  float* out = (float*)d_out;
  // d_out scratch layout (consumed before out_proj overwrites [0,16.7M)):
  float* res    = out;                                  // 8,388,608 f32 residual
  float* e2     = out + 8388608;                        // 8192 f32 (np bits)
  double* part  = (double*)(out + 8404992);             // 4096 f64 (8 stages x 512 blocks)
  unsigned short* cb_h = (unsigned short*)(out + 9000000);   // 2,097,152 bf16 (4MB)
  unsigned short* cb_l = (unsigned short*)(out + 10500000);  // 4MB
  float* idx_f  = out + 16777216;                       // 262,144 f32
  float* c_out  = out + 17039360;                       // 1 f32

  hipLaunchKernelGGL(e2_np_kernel, dim3(32), dim3(256), 0, stream, cb, e2);
  hipLaunchKernelGGL(presplit_kernel, dim3(1024), dim3(256), 0, stream, cb, cb_h, cb_l);
  hipLaunchKernelGGL(in_proj_kernel, dim3(512, 4), dim3(256), 0, stream, x, in_w, in_b, res);
  for (int s = 0; s < NQ; ++s) {
    hipLaunchKernelGGL(stage_kernel, dim3(STG_BLOCKS), dim3(256), 0, stream,
                       cb, e2, cb_h, cb_l, res, idx_f, part, s);
  }
  hipLaunchKernelGGL(finalize_kernel, dim3(1), dim3(64), 0, stream, part, c_out);
  hipLaunchKernelGGL(out_proj_kernel, dim3(512, 8), dim3(256), 0, stream, cb, idx_f, out_w, out_b, out);
}

// Round 12
// 1691.070 us; speedup vs baseline: 1.5221x; 1.4659x over previous
//
#include <hip/hip_runtime.h>
#include <math.h>

#define DC 256
#define NBINS 1024
#define NQ 8
#define NTOK 32768      // B*T
#define D_IN 512
#define DCH 32
#define TOK 64          // tokens per stage-block -> 512 blocks/stage
#define STG_BLOCKS (NTOK / TOK)
#define MARGIN 5e-3f    // fast(MFMA) top-2 gap below which we re-rank with np bits

typedef __attribute__((ext_vector_type(8))) short short8v;   // 8 bf16 (4 VGPR)
typedef __attribute__((ext_vector_type(4))) float f32x4;

// ---- bf16 helpers (RNE, matches hw cvt) ----
__device__ __forceinline__ unsigned short f2bf(float x) {
  unsigned u = __float_as_uint(x);
  return (unsigned short)((u + 0x7fffu + ((u >> 16) & 1u)) >> 16);
}
__device__ __forceinline__ float bf2f(unsigned short h) {
  return __uint_as_float(((unsigned)h) << 16);
}
__device__ __forceinline__ void store8s(unsigned short* dst, const unsigned short* v) {
  uint4 u;
  u.x = v[0] | ((unsigned)v[1] << 16); u.y = v[2] | ((unsigned)v[3] << 16);
  u.z = v[4] | ((unsigned)v[5] << 16); u.w = v[6] | ((unsigned)v[7] << 16);
  *reinterpret_cast<uint4*>(dst) = u;
}
__device__ __forceinline__ short8v load8s(const unsigned short* p) {
  return __builtin_bit_cast(short8v, *reinterpret_cast<const float4*>(p));
}

// ---- numpy pairwise_sum bit-emulation (8 accumulators, 128-block) ----
__device__ __forceinline__ float np_sumsq128(const float* a) {
#pragma clang fp contract(off)
  float r0 = a[0] * a[0], r1 = a[1] * a[1], r2 = a[2] * a[2], r3 = a[3] * a[3];
  float r4 = a[4] * a[4], r5 = a[5] * a[5], r6 = a[6] * a[6], r7 = a[7] * a[7];
  for (int i = 8; i < 128; i += 8) {
    r0 += a[i + 0] * a[i + 0]; r1 += a[i + 1] * a[i + 1];
    r2 += a[i + 2] * a[i + 2]; r3 += a[i + 3] * a[i + 3];
    r4 += a[i + 4] * a[i + 4]; r5 += a[i + 5] * a[i + 5];
    r6 += a[i + 6] * a[i + 6]; r7 += a[i + 7] * a[i + 7];
  }
  return ((r0 + r1) + (r2 + r3)) + ((r4 + r5) + (r6 + r7));
}
__device__ __forceinline__ float np_sumsq256(const float* a) {
#pragma clang fp contract(off)
  float lo = np_sumsq128(a);
  float hi = np_sumsq128(a + 128);
  return lo + hi;
}

// ---------------- K0: codebook squared norms, np-pairwise bits ----------------
__global__ void e2_np_kernel(const float* __restrict__ cb, float* __restrict__ e2) {
  int b = blockIdx.x * 256 + threadIdx.x;
  e2[b] = np_sumsq256(cb + (size_t)b * DC);
}

// ---------------- K0b: codebook bf16 hi/lo pre-split ----------------
// layout: [s][k8 0..31][bin 0..1023][8] bf16
__global__ void presplit_kernel(const float* __restrict__ cb,
                                unsigned short* __restrict__ cb_h,
                                unsigned short* __restrict__ cb_l) {
  int id = blockIdx.x * 256 + threadIdx.x;   // (s*32+k8)*1024 + bin
  int sk = id >> 10, bin = id & 1023;
  int s = sk >> 5, k8 = sk & 31;
  const float* src = cb + ((size_t)s * NBINS + bin) * DC + k8 * 8;
  unsigned short hh[8], ll[8];
#pragma unroll
  for (int j = 0; j < 8; ++j) {
    float x = src[j];
    unsigned short h = f2bf(x);
    hh[j] = h;
    ll[j] = f2bf(x - bf2f(h));
  }
  store8s(cb_h + (size_t)id * 8, hh);
  store8s(cb_l + (size_t)id * 8, ll);
}

// ---------------- K1: in-projection, OpenBLAS-sgemm bit-emulation ----------------
__global__ __launch_bounds__(256) void in_proj_kernel(
    const float* __restrict__ x, const float* __restrict__ in_w,
    const float* __restrict__ in_b, float* __restrict__ res) {
  __shared__ __align__(16) float aT[DCH][68];
  __shared__ __align__(16) float bT[DCH][68];
  const int thr = threadIdx.x;
  const int tx = thr & 15, ty = thr >> 4;
  const int m0 = blockIdx.x * 64, n0 = blockIdx.y * 64;
  float acc[4][4] = {};
  float s1[4][4] = {};
  for (int kc = 0; kc < D_IN; kc += DCH) {
    if (kc == 384) {
#pragma unroll
      for (int i = 0; i < 4; ++i)
#pragma unroll
        for (int j = 0; j < 4; ++j) { s1[i][j] = acc[i][j]; acc[i][j] = 0.f; }
    }
    __syncthreads();
#pragma unroll
    for (int i = 0; i < 2; ++i) {
      int q = thr + 256 * i;
      int m = q >> 3, kk = (q & 7) << 2;
      float4 v = *reinterpret_cast<const float4*>(x + (size_t)(m0 + m) * D_IN + kc + kk);
      aT[kk + 0][m] = v.x; aT[kk + 1][m] = v.y; aT[kk + 2][m] = v.z; aT[kk + 3][m] = v.w;
      float4 w = *reinterpret_cast<const float4*>(in_w + (size_t)(n0 + m) * D_IN + kc + kk);
      bT[kk + 0][m] = w.x; bT[kk + 1][m] = w.y; bT[kk + 2][m] = w.z; bT[kk + 3][m] = w.w;
    }
    __syncthreads();
#pragma unroll 8
    for (int d = 0; d < DCH; ++d) {
      float4 a = *reinterpret_cast<const float4*>(&aT[d][ty * 4]);
      float4 b = *reinterpret_cast<const float4*>(&bT[d][tx * 4]);
      float av[4] = {a.x, a.y, a.z, a.w};
      float bv[4] = {b.x, b.y, b.z, b.w};
#pragma unroll
      for (int i = 0; i < 4; ++i)
#pragma unroll
        for (int j = 0; j < 4; ++j) acc[i][j] = fmaf(av[i], bv[j], acc[i][j]);
    }
  }
#pragma unroll
  for (int i = 0; i < 4; ++i) {
    int m = m0 + ty * 4 + i, n = n0 + tx * 4;
    float4 hv;
#pragma unroll
    for (int j = 0; j < 4; ++j) {
#pragma clang fp contract(off)
      float c = s1[i][j] + acc[i][j];
      float pre = c + in_b[n + j];
      ((float*)&hv)[j] = tanhf(pre);
    }
    *reinterpret_cast<float4*>(res + (size_t)m * DC + n) = hv;
  }
}

// ---------------- K2: per-stage RVQ — MFMA score + np re-rank + update ----------------
// Per-stage launch (codebook L2-resident). 2 blocks/CU forced. Pass-major MFMA
// interleave (16 independent accs between same-acc reuses). A(-2r hi/lo) in LDS.
__global__ __launch_bounds__(256, 2) void stage_kernel(
    const float* __restrict__ cb, const float* __restrict__ e2,
    const unsigned short* __restrict__ cb_h, const unsigned short* __restrict__ cb_l,
    float* __restrict__ res, float* __restrict__ idx_f, double* __restrict__ partial,
    int s) {
  __shared__ __align__(16) unsigned short a_hi[32 * 64 * 8];  // 32KB
  __shared__ __align__(16) unsigned short a_lo[32 * 64 * 8];  // 32KB
  __shared__ float m1s[4 * 64], m2s[4 * 64];
  __shared__ int   i1s[4 * 64];
  __shared__ int   win_l[64], flag_l[64];
  __shared__ __align__(16) float rrow_s[256];
  __shared__ float redf[4];
  __shared__ int   redi[4];
  __shared__ double wsum[4];

  const int thr = threadIdx.x;
  const int lane = thr & 63;
  const int w = thr >> 6;        // wave 0..3 -> bins [w*256, w*256+256)
  const int lg = lane >> 4;      // k-subgroup (A/B), row-subgroup (C)
  const int lc = lane & 15;      // A row-in-tile / B,C col(bin)-in-tile
  const int m0 = blockIdx.x * TOK;
  const float* cbs = cb + (size_t)s * NBINS * DC;
  const float* e2s = e2 + (size_t)s * NBINS;
  const unsigned short* bhp = cb_h + (size_t)s * (32 * 1024 * 8);
  const unsigned short* blp = cb_l + (size_t)s * (32 * 1024 * 8);
  double sqacc = 0.0;

  // ---- A build: -2*r as bf16 hi/lo into LDS ----
  {
    int row = thr >> 2, d0 = (thr & 3) << 6;
    const float* rrow = res + (size_t)(m0 + row) * DC + d0;
#pragma unroll
    for (int c = 0; c < 8; ++c) {
      float4 r0 = *reinterpret_cast<const float4*>(rrow + c * 8);
      float4 r1 = *reinterpret_cast<const float4*>(rrow + c * 8 + 4);
      float rv[8] = {r0.x, r0.y, r0.z, r0.w, r1.x, r1.y, r1.z, r1.w};
      unsigned short hh[8], ll[8];
#pragma unroll
      for (int j = 0; j < 8; ++j) {
        float xv = -2.0f * rv[j];
        unsigned short h = f2bf(xv);
        hh[j] = h; ll[j] = f2bf(xv - bf2f(h));
      }
      int k8 = (d0 >> 3) + c;
      store8s(a_hi + ((size_t)k8 * 64 + row) * 8, hh);
      store8s(a_lo + ((size_t)k8 * 64 + row) * 8, ll);
    }
  }
  m1s[thr] = 3.4028235e38f; m2s[thr] = 3.4028235e38f; i1s[thr] = 0;
  __syncthreads();

  // ---- MFMA scoring: dist = e2 - 2*r.e, 3-pass bf16 hi/lo, pass-major ----
  for (int c = 0; c < 4; ++c) {
    const int bbase = w * 256 + c * 64;
    f32x4 acc[4][4];
#pragma unroll
    for (int nt = 0; nt < 4; ++nt) {
      float ev = e2s[bbase + nt * 16 + lc];
      f32x4 iv = {ev, ev, ev, ev};
#pragma unroll
      for (int rt = 0; rt < 4; ++rt) acc[rt][nt] = iv;
    }
#pragma unroll 2
    for (int kstep = 0; kstep < 8; ++kstep) {
      short8v ah[4], al[4];
#pragma unroll
      for (int rt = 0; rt < 4; ++rt) {
        int off = ((kstep * 4 + lg) * 64 + rt * 16 + lc) * 8;
        ah[rt] = load8s(a_hi + off);
        al[rt] = load8s(a_lo + off);
      }
      short8v bh[4], bl[4];
#pragma unroll
      for (int nt = 0; nt < 4; ++nt) {
        size_t boff = ((size_t)(kstep * 4 + lg) * 1024 + bbase + nt * 16 + lc) * 8;
        bh[nt] = load8s(bhp + boff);
        bl[nt] = load8s(blp + boff);
      }
      // pass-major: 16 independent MFMAs between reuses of the same acc
#pragma unroll
      for (int nt = 0; nt < 4; ++nt)
#pragma unroll
        for (int rt = 0; rt < 4; ++rt)
          acc[rt][nt] = __builtin_amdgcn_mfma_f32_16x16x32_bf16(ah[rt], bh[nt], acc[rt][nt], 0, 0, 0);
#pragma unroll
      for (int nt = 0; nt < 4; ++nt)
#pragma unroll
        for (int rt = 0; rt < 4; ++rt)
          acc[rt][nt] = __builtin_amdgcn_mfma_f32_16x16x32_bf16(ah[rt], bl[nt], acc[rt][nt], 0, 0, 0);
#pragma unroll
      for (int nt = 0; nt < 4; ++nt)
#pragma unroll
        for (int rt = 0; rt < 4; ++rt)
          acc[rt][nt] = __builtin_amdgcn_mfma_f32_16x16x32_bf16(al[rt], bh[nt], acc[rt][nt], 0, 0, 0);
    }
    // fold this chunk into per-wave LDS top-2 (bins ascending)
#pragma unroll
    for (int rt = 0; rt < 4; ++rt)
#pragma unroll
      for (int reg = 0; reg < 4; ++reg) {
        float m1 = 3.4028235e38f, m2 = 3.4028235e38f; int i1 = 0;
#pragma unroll
        for (int nt = 0; nt < 4; ++nt) {
          float v = acc[rt][nt][reg];
          int b = bbase + nt * 16 + lc;
          if (v < m1) { m2 = m1; m1 = v; i1 = b; }
          else m2 = fminf(m2, v);
        }
#pragma unroll
        for (int msk = 1; msk < 16; msk <<= 1) {
          float om1 = __shfl_xor(m1, msk, 64);
          float om2 = __shfl_xor(m2, msk, 64);
          int   oi1 = __shfl_xor(i1, msk, 64);
          if (om1 < m1 || (om1 == m1 && oi1 < i1)) { m2 = fminf(m1, om2); m1 = om1; i1 = oi1; }
          else m2 = fminf(m2, om1);
        }
        if (lc == 0) {
          int sidx = w * 64 + rt * 16 + lg * 4 + reg;
          float pm1 = m1s[sidx], pm2 = m2s[sidx]; int pi1 = i1s[sidx];
          if (m1 < pm1 || (m1 == pm1 && i1 < pi1)) {
            m1s[sidx] = m1; m2s[sidx] = fminf(pm1, m2); i1s[sidx] = i1;
          } else {
            m2s[sidx] = fminf(pm2, m1);
          }
        }
      }
  }
  __syncthreads();
  // final per-row merge across waves -> winner + margin flag
  if (thr < TOK) {
    float m1 = m1s[thr], m2 = m2s[thr]; int i1 = i1s[thr];
#pragma unroll
    for (int ww = 1; ww < 4; ++ww) {
      float om1 = m1s[ww * 64 + thr], om2 = m2s[ww * 64 + thr];
      int oi1 = i1s[ww * 64 + thr];
      if (om1 < m1 || (om1 == m1 && oi1 < i1)) { m2 = fminf(m1, om2); m1 = om1; i1 = oi1; }
      else m2 = fminf(m2, om1);
    }
    win_l[thr] = i1;
    flag_l[thr] = (m2 - m1 < MARGIN) ? 1 : 0;
  }
  __syncthreads();
  // ---- np-bit re-rank for flagged rows (rare; uniform branch) ----
  for (int row = 0; row < TOK; ++row) {
    if (!flag_l[row]) continue;
    if (thr < 64)
      reinterpret_cast<float4*>(rrow_s)[thr] =
          reinterpret_cast<const float4*>(res + (size_t)(m0 + row) * DC)[thr];
    __syncthreads();
    float r2 = np_sumsq256(rrow_s);
    float best = 3.4028235e38f; int bb = 0;
#pragma unroll
    for (int jj = 0; jj < 4; ++jj) {
      int b = thr * 4 + jj;
      const float4* e4 = reinterpret_cast<const float4*>(cbs + (size_t)b * DC);
      const float4* r4 = reinterpret_cast<const float4*>(rrow_s);
      float accv = 0.f;
      for (int q = 0; q < 64; ++q) {   // d ascending: sgemm-chain bits
        float4 ev = e4[q], rv = r4[q];
        accv = fmaf(rv.x, ev.x, accv);
        accv = fmaf(rv.y, ev.y, accv);
        accv = fmaf(rv.z, ev.z, accv);
        accv = fmaf(rv.w, ev.w, accv);
      }
      {
#pragma clang fp contract(off)
        float t = r2 - 2.0f * accv;
        float dist = t + e2s[b];
        if (dist < best) { best = dist; bb = b; }
      }
    }
#pragma unroll
    for (int msk = 1; msk < 64; msk <<= 1) {
      float ov = __shfl_xor(best, msk, 64);
      int   ob = __shfl_xor(bb, msk, 64);
      if (ov < best || (ov == best && ob < bb)) { best = ov; bb = ob; }
    }
    if (lane == 0) { redf[w] = best; redi[w] = bb; }
    __syncthreads();
    if (thr == 0) {
      float bs = redf[0]; int bfin = redi[0];
#pragma unroll
      for (int ww = 1; ww < 4; ++ww)
        if (redf[ww] < bs || (redf[ww] == bs && redi[ww] < bfin)) { bs = redf[ww]; bfin = redi[ww]; }
      win_l[row] = bfin;
    }
    __syncthreads();
  }
  // ---- residual update (np state bits) + commit acc ----
  {
    int row = thr >> 2, d0 = (thr & 3) << 6;
    int wbin = win_l[row];
    const float* erow = cbs + (size_t)wbin * DC + d0;
    float* rrow = res + (size_t)(m0 + row) * DC + d0;
#pragma unroll
    for (int c = 0; c < 8; ++c) {
      float4 r0 = *reinterpret_cast<const float4*>(rrow + c * 8);
      float4 r1 = *reinterpret_cast<const float4*>(rrow + c * 8 + 4);
      float4 e0 = *reinterpret_cast<const float4*>(erow + c * 8);
      float4 e1 = *reinterpret_cast<const float4*>(erow + c * 8 + 4);
      float nv[8] = {r0.x - e0.x, r0.y - e0.y, r0.z - e0.z, r0.w - e0.w,
                     r1.x - e1.x, r1.y - e1.y, r1.z - e1.z, r1.w - e1.w};
#pragma unroll
      for (int j = 0; j < 8; ++j) sqacc += (double)nv[j] * nv[j];
      *reinterpret_cast<float4*>(rrow + c * 8) = (float4){nv[0], nv[1], nv[2], nv[3]};
      *reinterpret_cast<float4*>(rrow + c * 8 + 4) = (float4){nv[4], nv[5], nv[6], nv[7]};
    }
    if (thr < TOK) idx_f[(size_t)s * NTOK + m0 + thr] = (float)win_l[thr];
  }
  // deterministic per-block commit partial (fp64)
#pragma unroll
  for (int msk = 1; msk < 64; msk <<= 1) sqacc += __shfl_xor(sqacc, msk, 64);
  if (lane == 0) wsum[w] = sqacc;
  __syncthreads();
  if (thr == 0) {
    double t = 0.0;
#pragma unroll
    for (int ww = 0; ww < 4; ++ww) t += wsum[ww];
    partial[(size_t)s * STG_BLOCKS + blockIdx.x] = t;
  }
}

// ---------------- K4: finalize commit loss (fixed order, 8*512 partials) ----------------
__global__ void finalize_kernel(const double* __restrict__ partial, float* __restrict__ out_last) {
  __shared__ double acc_s[64];
  int t = threadIdx.x;
  double a = 0.0;
  for (int i = 0; i < 64; ++i) a += partial[(size_t)t * 64 + i];
  acc_s[t] = a;
  __syncthreads();
  if (t == 0) {
    double tot = 0.0;
    for (int i = 0; i < 64; ++i) tot += acc_s[i];
    out_last[0] = (float)(0.1 * tot / 8388608.0);
  }
}

// ---------------- K3: out-projection GEMM from gathered quantized ----------------
__global__ __launch_bounds__(256) void out_proj_kernel(
    const float* __restrict__ cb, const float* __restrict__ idx_f,
    const float* __restrict__ out_w, const float* __restrict__ out_b,
    float* __restrict__ out) {
  __shared__ __align__(16) float aT[DCH][68];
  __shared__ __align__(16) float bT[DCH][68];
  __shared__ int idx_l[NQ][64];
  const int thr = threadIdx.x;
  const int tx = thr & 15, ty = thr >> 4;
  const int m0 = blockIdx.x * 64, n0 = blockIdx.y * 64;
#pragma unroll
  for (int i = 0; i < 2; ++i) {
    int q = thr + 256 * i;
    int s = q >> 6, m = q & 63;
    idx_l[s][m] = (int)idx_f[(size_t)s * NTOK + m0 + m];
  }
  float acc[4][4] = {};
  for (int kc = 0; kc < DC; kc += DCH) {
    __syncthreads();
#pragma unroll
    for (int i = 0; i < 2; ++i) {
      int q = thr + 256 * i;
      int m = q >> 3, kk = (q & 7) << 2;
      float4 v = {0.f, 0.f, 0.f, 0.f};
#pragma unroll
      for (int s = 0; s < NQ; ++s) {
        const float4 e = *reinterpret_cast<const float4*>(
            cb + ((size_t)s * NBINS + idx_l[s][m]) * DC + kc + kk);
        v.x += e.x; v.y += e.y; v.z += e.z; v.w += e.w;
      }
      aT[kk + 0][m] = v.x; aT[kk + 1][m] = v.y; aT[kk + 2][m] = v.z; aT[kk + 3][m] = v.w;
      float4 wv = *reinterpret_cast<const float4*>(out_w + (size_t)(n0 + m) * DC + kc + kk);
      bT[kk + 0][m] = wv.x; bT[kk + 1][m] = wv.y; bT[kk + 2][m] = wv.z; bT[kk + 3][m] = wv.w;
    }
    __syncthreads();
#pragma unroll 8
    for (int d = 0; d < DCH; ++d) {
      float4 a = *reinterpret_cast<const float4*>(&aT[d][ty * 4]);
      float4 b = *reinterpret_cast<const float4*>(&bT[d][tx * 4]);
      float av[4] = {a.x, a.y, a.z, a.w};
      float bv[4] = {b.x, b.y, b.z, b.w};
#pragma unroll
      for (int i = 0; i < 4; ++i)
#pragma unroll
        for (int j = 0; j < 4; ++j) acc[i][j] = fmaf(av[i], bv[j], acc[i][j]);
    }
  }
#pragma unroll
  for (int i = 0; i < 4; ++i) {
    int m = m0 + ty * 4 + i, n = n0 + tx * 4;
    float4 o;
    o.x = acc[i][0] + out_b[n + 0];
    o.y = acc[i][1] + out_b[n + 1];
    o.z = acc[i][2] + out_b[n + 2];
    o.w = acc[i][3] + out_b[n + 3];
    *reinterpret_cast<float4*>(out + (size_t)m * D_IN + n) = o;
  }
}

extern "C" void kernel_launch(void* const* d_in, const int* in_sizes, int n_in,
                              void* d_out, int out_size, void* d_ws, size_t ws_size,
                              hipStream_t stream) {
  (void)in_sizes; (void)n_in; (void)out_size; (void)d_ws; (void)ws_size;
  const float* x     = (const float*)d_in[0];
  const float* in_w  = (const float*)d_in[1];
  const float* in_b  = (const float*)d_in[2];
  const float* out_w = (const float*)d_in[3];
  const float* out_b = (const float*)d_in[4];
  const float* cb    = (const float*)d_in[5];
  float* out = (float*)d_out;
  // d_out scratch layout (consumed before out_proj overwrites [0,16.7M)):
  float* res    = out;                                  // 8,388,608 f32 residual
  float* e2     = out + 8388608;                        // 8192 f32 (np bits)
  double* part  = (double*)(out + 8404992);             // 4096 f64 (8 stages x 512 blocks)
  unsigned short* cb_h = (unsigned short*)(out + 9000000);   // 2,097,152 bf16 (4MB)
  unsigned short* cb_l = (unsigned short*)(out + 10500000);  // 4MB
  float* idx_f  = out + 16777216;                       // 262,144 f32
  float* c_out  = out + 17039360;                       // 1 f32

  hipLaunchKernelGGL(e2_np_kernel, dim3(32), dim3(256), 0, stream, cb, e2);
  hipLaunchKernelGGL(presplit_kernel, dim3(1024), dim3(256), 0, stream, cb, cb_h, cb_l);
  hipLaunchKernelGGL(in_proj_kernel, dim3(512, 4), dim3(256), 0, stream, x, in_w, in_b, res);
  for (int s = 0; s < NQ; ++s) {
    hipLaunchKernelGGL(stage_kernel, dim3(STG_BLOCKS), dim3(256), 0, stream,
                       cb, e2, cb_h, cb_l, res, idx_f, part, s);
  }
  hipLaunchKernelGGL(finalize_kernel, dim3(1), dim3(64), 0, stream, part, c_out);
  hipLaunchKernelGGL(out_proj_kernel, dim3(512, 8), dim3(256), 0, stream, cb, idx_f, out_w, out_b, out);
}